// Round 6
// baseline (912.122 us; speedup 1.0000x reference)
//
#include <hip/hip_runtime.h>
#include <hip/hip_bf16.h>
#include <math.h>

#define B_  128
#define S_  2048
#define DI  512
#define DC  512

typedef __attribute__((ext_vector_type(8))) __bf16 bf16x8;
typedef __attribute__((ext_vector_type(4))) float  f32x4;
typedef __attribute__((ext_vector_type(8))) unsigned short us8;

__device__ __forceinline__ float fast_tanh(float x) {
    float e = __expf(2.f * x);
    return 1.f - 2.f * __builtin_amdgcn_rcpf(e + 1.f);
}

__device__ __forceinline__ unsigned short f2bf(float f) {
    unsigned int u = __float_as_uint(f);
    u += 0x7FFF + ((u >> 16) & 1);   // RNE
    return (unsigned short)(u >> 16);
}

__device__ __forceinline__ unsigned int pk2(float a, float b) {
    union { __hip_bfloat162 h; unsigned int u; } c;
    c.h = __float22bfloat162_rn(make_float2(a, b));
    return c.u;
}

__device__ __forceinline__ float bf2f(unsigned int lo16) {
    return __uint_as_float(lo16 << 16);
}

// ---- fused prep: qb (blocks 0..511) + WtF repack (blocks 512..639) ----
__global__ __launch_bounds__(256) void prep_kernel(
    const float* __restrict__ input, const float* __restrict__ W_in,
    const float* __restrict__ b_in, const float* __restrict__ b_ctx,
    const float* __restrict__ W_ctx,
    float* __restrict__ qb, unsigned short* __restrict__ WtF)
{
    __shared__ float sIn[DI];
    __shared__ float part[2][128];
    const int bx = blockIdx.x, t = threadIdx.x;
    if (bx < 512) {
        int b = bx >> 2, cg = bx & 3;
        for (int i = t; i < DI; i += 256) sIn[i] = input[b * DI + i];
        __syncthreads();
        int e = cg * 128 + (t & 127);
        int dh = t >> 7;
        float a = 0.f;
        const float* wp = W_in + (size_t)(dh * 256) * DC + e;
        #pragma unroll 4
        for (int d = 0; d < 256; ++d) a += sIn[dh * 256 + d] * wp[(size_t)d * DC];
        part[dh][t & 127] = a;
        __syncthreads();
        if (t < 128) {
            int ee = cg * 128 + t;
            qb[b * DC + ee] = b_in[ee] + b_ctx[ee] + part[0][t] + part[1][t];
        }
    } else {
        // WtF[s][g][lane][j] = bf16(W_ctx[s*32 + (lane>>4)*8 + j][g*16 + (lane&15)])
        int tid = (bx - 512) * 256 + t;       // [0, 16*32*64)
        int s   = tid >> 11;
        int rem = tid & 2047;
        int g   = rem >> 6;
        int l   = rem & 63;
        int c   = g * 16 + (l & 15);
        int k0  = s * 32 + (l >> 4) * 8;
        us8 wv;
        #pragma unroll
        for (int j = 0; j < 8; ++j)
            wv[j] = f2bf(W_ctx[(size_t)(k0 + j) * DC + c]);
        *(us8*)(WtF + (size_t)tid * 8) = wv;
    }
}

// ---- score kernel helpers ----
struct Stage { float4 va[2], vb[2]; };

__device__ __forceinline__ void load_half(Stage& st, const float* __restrict__ ctx,
                                          int r0, int w, int lane) {
    #pragma unroll
    for (int i = 0; i < 2; ++i) {
        const float4* src = (const float4*)(ctx + (size_t)(r0 + i * 16 + w) * DC + lane * 8);
        st.va[i] = src[0]; st.vb[i] = src[1];
    }
}

__device__ __forceinline__ void write_half(const Stage& st, unsigned short* buf,
                                           int rbase, int w, int lane) {
    #pragma unroll
    for (int i = 0; i < 2; ++i) {
        int r = rbase + i * 16 + w;
        uint4 p4 = {pk2(st.va[i].x, st.va[i].y), pk2(st.va[i].z, st.va[i].w),
                    pk2(st.vb[i].x, st.vb[i].y), pk2(st.vb[i].z, st.vb[i].w)};
        *(uint4*)((char*)buf + ((r * 1024 + lane * 16) ^ ((r & 7) << 4))) = p4;
    }
}

__device__ __forceinline__ void kchunk(f32x4 (&acc)[4][2], const unsigned short* buf,
                                       const unsigned short* __restrict__ WtF,
                                       int s0, int w, int lr, int half, int lane) {
    #pragma unroll
    for (int s = s0; s < s0 + 8; ++s) {
        bf16x8 bfr[2];
        const us8* wsrc = (const us8*)(WtF + (((size_t)s * 32 + w * 2) * 64 + lane) * 8);
        #pragma unroll
        for (int fn = 0; fn < 2; ++fn)
            bfr[fn] = *(const bf16x8*)(wsrc + fn * 64);
        bf16x8 af[4];
        #pragma unroll
        for (int fm = 0; fm < 4; ++fm) {
            int r = fm * 16 + lr;
            af[fm] = *(const bf16x8*)((const char*)buf +
                        ((r * 1024 + s * 64 + half * 16) ^ ((r & 7) << 4)));
        }
        #pragma unroll
        for (int fm = 0; fm < 4; ++fm)
            #pragma unroll
            for (int fn = 0; fn < 2; ++fn)
                acc[fm][fn] = __builtin_amdgcn_mfma_f32_16x16x32_bf16(
                    af[fm], bfr[fn], acc[fm][fn], 0, 0, 0);
    }
}

// Persistent fused score kernel: 256 blocks x 1024 threads (16 waves, 1 block/CU),
// 16 tiles of 64 rows each, double-buffered half-tile staging.
// Wave w (0..15) owns cols [w*32, +32) over all 64 rows: acc[4][2].
__global__ __launch_bounds__(1024) void score_kernel(
    const float* __restrict__ ctx,          // [B*S, DC] fp32
    const unsigned short* __restrict__ WtF, // fragment-ordered bf16
    const float* __restrict__ qb,           // [B][DC]
    const float* __restrict__ wsc,          // [DC]
    const int* __restrict__ mask,           // [B*S]
    float* __restrict__ scores_ws,          // [B*S]
    float* __restrict__ pv_ws,              // [ntiles][512]
    float* __restrict__ ml_ws)              // [ntiles][2]
{
    __shared__ __align__(16) unsigned short ctxs[2][64 * 512]; // 2 x 64 KB
    __shared__ float sred[16][64];
    __shared__ float sp[64];
    __shared__ float pvpart[2][512];

    const int t = threadIdx.x;
    const int bx = blockIdx.x;
    const int lane = t & 63;
    const int w = t >> 6;                   // wave 0..15 = col slice
    const int lr = lane & 15, half = lane >> 4;

    const float wv0 = wsc[w * 32 + lr];
    const float wv1 = wsc[w * 32 + 16 + lr];

    Stage st;
    // prologue: stage tile0 (both halves), then issue tile1 half0
    load_half(st, ctx, bx * 64, w, lane);
    write_half(st, ctxs[0], 0, w, lane);
    load_half(st, ctx, bx * 64 + 32, w, lane);
    write_half(st, ctxs[0], 32, w, lane);
    load_half(st, ctx, (bx + 256) * 64, w, lane);   // tile1 half0, stays in flight
    __syncthreads();

    int cur = 0;
    #pragma unroll 1
    for (int it = 0; it < 16; ++it) {
        const int tile = bx + it * 256;
        const int row0 = tile * 64;
        const int bidx = tile >> 5;

        f32x4 acc[4][2] = {};

        if (it < 15) {  // write next-tile half0 (regs loaded last iter), issue half1
            write_half(st, ctxs[cur ^ 1], 0, w, lane);
            load_half(st, ctx, (tile + 256) * 64 + 32, w, lane);
        }
        kchunk(acc, ctxs[cur], WtF, 0, w, lr, half, lane);
        if (it < 15) {  // write half1, issue tile+2 half0
            write_half(st, ctxs[cur ^ 1], 32, w, lane);
            if (it < 14) load_half(st, ctx, (tile + 512) * 64, w, lane);
        }
        kchunk(acc, ctxs[cur], WtF, 8, w, lr, half, lane);

        // epilogue: tanh fold + 16-lane row reduce
        const float qv0 = qb[bidx * DC + w * 32 + lr];
        const float qv1 = qb[bidx * DC + w * 32 + 16 + lr];
        #pragma unroll
        for (int fm = 0; fm < 4; ++fm) {
            #pragma unroll
            for (int reg = 0; reg < 4; ++reg) {
                float ssum = wv0 * fast_tanh(qv0 + acc[fm][0][reg])
                           + wv1 * fast_tanh(qv1 + acc[fm][1][reg]);
                #pragma unroll
                for (int m = 8; m >= 1; m >>= 1)
                    ssum += __shfl_xor(ssum, m, 64);
                if (lr == 0)
                    sred[w][fm * 16 + half * 4 + reg] = ssum;
            }
        }
        __syncthreads();

        if (t < 64) {                        // wave 0: block softmax partials
            float sc = 0.f;
            #pragma unroll
            for (int ww = 0; ww < 16; ++ww) sc += sred[ww][t];
            if (mask[row0 + t] != 0) sc = -1e30f;
            scores_ws[row0 + t] = sc;
            float mx = sc;
            #pragma unroll
            for (int m = 32; m >= 1; m >>= 1) mx = fmaxf(mx, __shfl_xor(mx, m, 64));
            float pe = __expf(sc - mx);
            sp[t] = pe;
            float ls = pe;
            #pragma unroll
            for (int m = 32; m >= 1; m >>= 1) ls += __shfl_xor(ls, m, 64);
            if (t == 0) {
                ml_ws[tile * 2]     = mx;
                ml_ws[tile * 2 + 1] = ls;
            }
        }
        __syncthreads();

        // pv partials from LDS
        {
            int col = t & 511, rh = t >> 9;
            float a0 = 0.f;
            #pragma unroll 8
            for (int s2 = 0; s2 < 32; ++s2) {
                int r = rh * 32 + s2;
                unsigned int u = *(const unsigned short*)
                    ((const char*)ctxs[cur] + ((r * 1024 + col * 2) ^ ((r & 7) << 4)));
                a0 += sp[r] * bf2f(u);
            }
            pvpart[rh][col] = a0;
        }
        __syncthreads();
        if (t < 512)
            pv_ws[(size_t)tile * 512 + t] = pvpart[0][t] + pvpart[1][t];

        cur ^= 1;
    }
}

// ---- fused tail: exact softmax merge + attn + ctxv + output GEMM ----
__global__ __launch_bounds__(256) void tail_kernel(
    const float* __restrict__ pv, const float* __restrict__ ml,
    const float* __restrict__ scores, const float* __restrict__ input,
    const float* __restrict__ W_out, const float* __restrict__ b_out,
    float* __restrict__ x, float* __restrict__ attn)
{
    int b = blockIdx.x, hf = blockIdx.y, t = threadIdx.x;
    __shared__ float sw[32];
    __shared__ float scm[1024];
    __shared__ float mlds[2];
    if (t < 32) {
        float m = ml[(b * 32 + t) * 2];
        float l = ml[(b * 32 + t) * 2 + 1];
        float mx = m;
        #pragma unroll
        for (int mm = 16; mm >= 1; mm >>= 1) mx = fmaxf(mx, __shfl_xor(mx, mm, 64));
        float wgt = __expf(m - mx);
        sw[t] = wgt;
        float ls = wgt * l;
        #pragma unroll
        for (int mm = 16; mm >= 1; mm >>= 1) ls += __shfl_xor(ls, mm, 64);
        if (t == 0) { mlds[0] = mx; mlds[1] = 1.f / ls; }
    }
    __syncthreads();
    const float mstar = mlds[0], invL = mlds[1];

    {   // ctxv -> scm[0..511]
        int d0 = t * 2;
        float c0 = 0.f, c1 = 0.f;
        #pragma unroll 4
        for (int j = 0; j < 32; ++j) {
            float wgt = sw[j];
            const float2 v = *(const float2*)(pv + (size_t)(b * 32 + j) * 512 + d0);
            c0 += wgt * v.x; c1 += wgt * v.y;
        }
        scm[d0] = c0 * invL; scm[d0 + 1] = c1 * invL;
    }
    for (int i = t; i < DI; i += 256) scm[512 + i] = input[b * DI + i];
    if (hf == 0) {
        #pragma unroll
        for (int k = 0; k < 8; ++k) {
            int s = k * 256 + t;
            attn[(size_t)b * S_ + s] = __expf(scores[(size_t)b * S_ + s] - mstar) * invL;
        }
    }
    __syncthreads();

    int e = hf * 256 + t;
    float a = b_out[e];
    #pragma unroll 4
    for (int d = 0; d < 1024; ++d) a += scm[d] * W_out[(size_t)d * DI + e];
    x[b * DI + e] = fast_tanh(a);
}

extern "C" void kernel_launch(void* const* d_in, const int* in_sizes, int n_in,
                              void* d_out, int out_size, void* d_ws, size_t ws_size,
                              hipStream_t stream) {
    const float* input = (const float*)d_in[0];
    const float* ctx   = (const float*)d_in[1];
    const int*   mask  = (const int*)d_in[2];
    const float* W_in  = (const float*)d_in[3];
    const float* b_in  = (const float*)d_in[4];
    const float* W_ctx = (const float*)d_in[5];
    const float* b_ctx = (const float*)d_in[6];
    const float* wsc   = (const float*)d_in[7];
    const float* W_out = (const float*)d_in[8];
    const float* b_out = (const float*)d_in[9];

    float* x_out = (float*)d_out;               // [B, DI]
    float* attn  = (float*)d_out + B_ * DI;     // [B, S]

    const int NTILE = (B_ * S_) / 64;           // 4096 tiles of 64 rows

    char* ws = (char*)d_ws;
    float* qb = (float*)ws;                    ws += (size_t)B_ * DC * 4;
    unsigned short* WtF = (unsigned short*)ws; ws += (size_t)DC * DC * 2;
    float* scores_ws = (float*)ws;             ws += (size_t)B_ * S_ * 4;
    float* pv_ws = (float*)ws;                 ws += (size_t)NTILE * 512 * 4;
    float* ml_ws = (float*)ws;                 ws += (size_t)NTILE * 2 * 4;

    prep_kernel<<<640, 256, 0, stream>>>(input, W_in, b_in, b_ctx, W_ctx, qb, WtF);
    score_kernel<<<256, 1024, 0, stream>>>(ctx, WtF, qb, wsc, mask,
                                           scores_ws, pv_ws, ml_ws);
    tail_kernel<<<dim3(B_, 2), 256, 0, stream>>>(pv_ws, ml_ws, scores_ws, input,
                                                 W_out, b_out, x_out, attn);
}

// Round 7
// 782.599 us; speedup vs baseline: 1.1655x; 1.1655x over previous
//
#include <hip/hip_runtime.h>
#include <hip/hip_bf16.h>
#include <math.h>

#define B_  128
#define S_  2048
#define DI  512
#define DC  512

typedef __attribute__((ext_vector_type(8))) __bf16 bf16x8;
typedef __attribute__((ext_vector_type(4))) float  f32x4;
typedef __attribute__((ext_vector_type(8))) unsigned short us8;

__device__ __forceinline__ float fast_tanh(float x) {
    float e = __expf(2.f * x);
    return 1.f - 2.f * __builtin_amdgcn_rcpf(e + 1.f);
}

__device__ __forceinline__ unsigned short f2bf(float f) {
    unsigned int u = __float_as_uint(f);
    u += 0x7FFF + ((u >> 16) & 1);   // RNE
    return (unsigned short)(u >> 16);
}

__device__ __forceinline__ unsigned int pk2(float a, float b) {
    union { __hip_bfloat162 h; unsigned int u; } c;
    c.h = __float22bfloat162_rn(make_float2(a, b));
    return c.u;
}

__device__ __forceinline__ float bf2f(unsigned int lo16) {
    return __uint_as_float(lo16 << 16);
}

// ---- fused prep: qb (blocks 0..511) + WtF repack (blocks 512..639) ----
__global__ __launch_bounds__(256) void prep_kernel(
    const float* __restrict__ input, const float* __restrict__ W_in,
    const float* __restrict__ b_in, const float* __restrict__ b_ctx,
    const float* __restrict__ W_ctx,
    float* __restrict__ qb, unsigned short* __restrict__ WtF)
{
    __shared__ float sIn[DI];
    __shared__ float part[2][128];
    const int bx = blockIdx.x, t = threadIdx.x;
    if (bx < 512) {
        int b = bx >> 2, cg = bx & 3;
        for (int i = t; i < DI; i += 256) sIn[i] = input[b * DI + i];
        __syncthreads();
        int e = cg * 128 + (t & 127);
        int dh = t >> 7;
        float a = 0.f;
        const float* wp = W_in + (size_t)(dh * 256) * DC + e;
        #pragma unroll 4
        for (int d = 0; d < 256; ++d) a += sIn[dh * 256 + d] * wp[(size_t)d * DC];
        part[dh][t & 127] = a;
        __syncthreads();
        if (t < 128) {
            int ee = cg * 128 + t;
            qb[b * DC + ee] = b_in[ee] + b_ctx[ee] + part[0][t] + part[1][t];
        }
    } else {
        // WtF[s][g][lane][j] = bf16(W_ctx[s*32 + (lane>>4)*8 + j][g*16 + (lane&15)])
        int tid = (bx - 512) * 256 + t;       // [0, 16*32*64)
        int s   = tid >> 11;
        int rem = tid & 2047;
        int g   = rem >> 6;
        int l   = rem & 63;
        int c   = g * 16 + (l & 15);
        int k0  = s * 32 + (l >> 4) * 8;
        us8 wv;
        #pragma unroll
        for (int j = 0; j < 8; ++j)
            wv[j] = f2bf(W_ctx[(size_t)(k0 + j) * DC + c]);
        *(us8*)(WtF + (size_t)tid * 8) = wv;
    }
}

// ---- score kernel helpers (512 threads) ----
struct StQ { float4 v[4]; };   // one 16-row x 512-col fp32 quarter, 16 regs

__device__ __forceinline__ void loadQ(StQ& st, const float* __restrict__ ctx,
                                      int rowq, int t) {
    const float* p = ctx + (size_t)(rowq + (t >> 5)) * DC + (t & 31) * 16;
    #pragma unroll
    for (int i = 0; i < 4; ++i) st.v[i] = ((const float4*)p)[i];
}

__device__ __forceinline__ void writeQ(const StQ& st, unsigned short* buf,
                                       int qrow, int t) {
    int r = qrow + (t >> 5);
    int cb = (t & 31) * 32;
    int sw = (r & 7) << 4;
    uint4 a = {pk2(st.v[0].x, st.v[0].y), pk2(st.v[0].z, st.v[0].w),
               pk2(st.v[1].x, st.v[1].y), pk2(st.v[1].z, st.v[1].w)};
    uint4 b = {pk2(st.v[2].x, st.v[2].y), pk2(st.v[2].z, st.v[2].w),
               pk2(st.v[3].x, st.v[3].y), pk2(st.v[3].z, st.v[3].w)};
    *(uint4*)((char*)buf + ((r * 1024 + cb) ^ sw))      = a;
    *(uint4*)((char*)buf + ((r * 1024 + cb + 16) ^ sw)) = b;
}

__device__ __forceinline__ void bfrLoad(bf16x8 (&b)[4],
                                        const unsigned short* __restrict__ WtF,
                                        int s, int w, int lane) {
    const us8* ws = (const us8*)(WtF + (((size_t)s * 32 + w * 4) * 64 + lane) * 8);
    #pragma unroll
    for (int fn = 0; fn < 4; ++fn) b[fn] = *(const bf16x8*)(ws + fn * 64);
}

#define RBAR() do { \
    asm volatile("s_waitcnt lgkmcnt(0)" ::: "memory"); \
    __builtin_amdgcn_s_barrier(); \
    __builtin_amdgcn_sched_barrier(0); \
} while (0)

#define KSTEP(s) do { \
    bf16x8 bn_[4]; bfrLoad(bn_, WtF, ((s) + 1) & 15, w, lane); \
    bf16x8 af_[4]; \
    _Pragma("unroll") \
    for (int fm = 0; fm < 4; ++fm) { \
        int r_ = fm * 16 + lr; \
        af_[fm] = *(const bf16x8*)((const char*)bufc + \
                    ((r_ * 1024 + (s) * 64 + half * 16) ^ ((r_ & 7) << 4))); \
    } \
    _Pragma("unroll") \
    for (int fm = 0; fm < 4; ++fm) \
        _Pragma("unroll") \
        for (int fn = 0; fn < 4; ++fn) \
            acc[fm][fn] = __builtin_amdgcn_mfma_f32_16x16x32_bf16( \
                af_[fm], bc[fn], acc[fm][fn], 0, 0, 0); \
    _Pragma("unroll") \
    for (int q_ = 0; q_ < 4; ++q_) bc[q_] = bn_[q_]; \
} while (0)

// Persistent fused score kernel: 256 blocks (1/CU) x 512 threads (8 waves,
// pinned 2 waves/SIMD -> 256-VGPR budget). 16 tiles of 64 rows per block,
// double-buffered quarter staging; raw barriers keep HBM loads in flight.
__global__ __launch_bounds__(512)
__attribute__((amdgpu_waves_per_eu(2, 2)))
void score_kernel(
    const float* __restrict__ ctx,          // [B*S, DC] fp32
    const unsigned short* __restrict__ WtF, // fragment-ordered bf16
    const float* __restrict__ qb,           // [B][DC]
    const float* __restrict__ wsc,          // [DC]
    const int* __restrict__ mask,           // [B*S]
    float* __restrict__ scores_ws,          // [B*S]
    float* __restrict__ pv_ws,              // [ntiles][512]
    float* __restrict__ ml_ws)              // [ntiles][2]
{
    __shared__ __align__(16) unsigned short ctxs[2][64 * 512]; // 2 x 64 KB
    __shared__ float sred[8][64];
    __shared__ float sp[64];

    const int t = threadIdx.x;
    const int bx = blockIdx.x;
    const int lane = t & 63;
    const int w = t >> 6;                   // wave 0..7 = col slice of 64
    const int lr = lane & 15, half = lane >> 4;

    float wv[4];
    #pragma unroll
    for (int fn = 0; fn < 4; ++fn) wv[fn] = wsc[w * 64 + fn * 16 + lr];

    StQ stA, stB;
    bf16x8 bc[4];
    // ---- prologue: fill buf0 with tile0; leave tile1 Q0/Q1 in flight ----
    {
        const int r0 = bx * 64, t1r = (bx + 256) * 64;
        loadQ(stA, ctx, r0, t);
        loadQ(stB, ctx, r0 + 16, t);
        writeQ(stA, ctxs[0], 0, t);
        loadQ(stA, ctx, r0 + 32, t);
        writeQ(stB, ctxs[0], 16, t);
        loadQ(stB, ctx, r0 + 48, t);
        writeQ(stA, ctxs[0], 32, t);
        loadQ(stA, ctx, t1r, t);
        writeQ(stB, ctxs[0], 48, t);
        loadQ(stB, ctx, t1r + 16, t);
        bfrLoad(bc, WtF, 0, w, lane);
    }
    RBAR();

    int cur = 0;
    #pragma unroll 1
    for (int it = 0; it < 16; ++it) {
        const int tile = bx + it * 256;
        const int row0 = tile * 64;
        const int bidx = tile >> 5;
        unsigned short* bufc = ctxs[cur];
        unsigned short* bufn = ctxs[cur ^ 1];
        const bool st1 = it < 15, st2 = it < 14;
        const int nr = row0 + 256 * 64, n2r = row0 + 512 * 64;

        f32x4 acc[4][4] = {};

        // phase A: write T+1 Q0, issue T+1 Q2
        if (st1) { writeQ(stA, bufn, 0, t);  loadQ(stA, ctx, nr + 32, t); }
        KSTEP(0); KSTEP(1); KSTEP(2); KSTEP(3);
        // phase B: write T+1 Q1, issue T+1 Q3
        if (st1) { writeQ(stB, bufn, 16, t); loadQ(stB, ctx, nr + 48, t); }
        KSTEP(4); KSTEP(5); KSTEP(6); KSTEP(7);
        // phase C: write T+1 Q2, issue T+2 Q0
        if (st1) writeQ(stA, bufn, 32, t);
        if (st2) loadQ(stA, ctx, n2r, t);
        KSTEP(8); KSTEP(9); KSTEP(10); KSTEP(11);
        // phase D: write T+1 Q3, issue T+2 Q1
        if (st1) writeQ(stB, bufn, 48, t);
        if (st2) loadQ(stB, ctx, n2r + 16, t);
        KSTEP(12); KSTEP(13); KSTEP(14); KSTEP(15);

        // ---- tail: tanh fold + row reduce ----
        float qv[4];
        #pragma unroll
        for (int fn = 0; fn < 4; ++fn)
            qv[fn] = qb[bidx * DC + w * 64 + fn * 16 + lr];
        #pragma unroll
        for (int fm = 0; fm < 4; ++fm) {
            #pragma unroll
            for (int reg = 0; reg < 4; ++reg) {
                float ssum = 0.f;
                #pragma unroll
                for (int fn = 0; fn < 4; ++fn)
                    ssum += wv[fn] * fast_tanh(qv[fn] + acc[fm][fn][reg]);
                #pragma unroll
                for (int m = 8; m >= 1; m >>= 1)
                    ssum += __shfl_xor(ssum, m, 64);
                if (lr == 0)
                    sred[w][fm * 16 + half * 4 + reg] = ssum;
            }
        }
        RBAR();

        if (t < 64) {                        // wave 0: block softmax partials
            float sc = sred[0][t] + sred[1][t] + sred[2][t] + sred[3][t]
                     + sred[4][t] + sred[5][t] + sred[6][t] + sred[7][t];
            if (mask[row0 + t] != 0) sc = -1e30f;
            scores_ws[row0 + t] = sc;
            float mx = sc;
            #pragma unroll
            for (int m = 32; m >= 1; m >>= 1) mx = fmaxf(mx, __shfl_xor(mx, m, 64));
            float pe = __expf(sc - mx);
            sp[t] = pe;
            float ls = pe;
            #pragma unroll
            for (int m = 32; m >= 1; m >>= 1) ls += __shfl_xor(ls, m, 64);
            if (t == 0) {
                ml_ws[tile * 2]     = mx;
                ml_ws[tile * 2 + 1] = ls;
            }
        }
        RBAR();

        // ---- pv partial: thread t = col t, rows from LDS ----
        {
            float a0 = 0.f;
            #pragma unroll 8
            for (int s2 = 0; s2 < 64; ++s2) {
                unsigned int u = *(const unsigned short*)
                    ((const char*)bufc + ((s2 * 1024 + t * 2) ^ ((s2 & 7) << 4)));
                a0 += sp[s2] * bf2f(u);
            }
            pv_ws[(size_t)tile * 512 + t] = a0;
        }
        RBAR();

        cur ^= 1;
    }
}

// ---- fused tail: exact softmax merge + attn + ctxv + output GEMM ----
__global__ __launch_bounds__(256) void tail_kernel(
    const float* __restrict__ pv, const float* __restrict__ ml,
    const float* __restrict__ scores, const float* __restrict__ input,
    const float* __restrict__ W_out, const float* __restrict__ b_out,
    float* __restrict__ x, float* __restrict__ attn)
{
    int b = blockIdx.x, hf = blockIdx.y, t = threadIdx.x;
    __shared__ float sw[32];
    __shared__ float scm[1024];
    __shared__ float mlds[2];
    if (t < 32) {
        float m = ml[(b * 32 + t) * 2];
        float l = ml[(b * 32 + t) * 2 + 1];
        float mx = m;
        #pragma unroll
        for (int mm = 16; mm >= 1; mm >>= 1) mx = fmaxf(mx, __shfl_xor(mx, mm, 64));
        float wgt = __expf(m - mx);
        sw[t] = wgt;
        float ls = wgt * l;
        #pragma unroll
        for (int mm = 16; mm >= 1; mm >>= 1) ls += __shfl_xor(ls, mm, 64);
        if (t == 0) { mlds[0] = mx; mlds[1] = 1.f / ls; }
    }
    __syncthreads();
    const float mstar = mlds[0], invL = mlds[1];

    {   // ctxv -> scm[0..511]
        int d0 = t * 2;
        float c0 = 0.f, c1 = 0.f;
        #pragma unroll 4
        for (int j = 0; j < 32; ++j) {
            float wgt = sw[j];
            const float2 v = *(const float2*)(pv + (size_t)(b * 32 + j) * 512 + d0);
            c0 += wgt * v.x; c1 += wgt * v.y;
        }
        scm[d0] = c0 * invL; scm[d0 + 1] = c1 * invL;
    }
    for (int i = t; i < DI; i += 256) scm[512 + i] = input[b * DI + i];
    if (hf == 0) {
        #pragma unroll
        for (int k = 0; k < 8; ++k) {
            int s = k * 256 + t;
            attn[(size_t)b * S_ + s] = __expf(scores[(size_t)b * S_ + s] - mstar) * invL;
        }
    }
    __syncthreads();

    int e = hf * 256 + t;
    float a = b_out[e];
    #pragma unroll 4
    for (int d = 0; d < 1024; ++d) a += scm[d] * W_out[(size_t)d * DI + e];
    x[b * DI + e] = fast_tanh(a);
}

extern "C" void kernel_launch(void* const* d_in, const int* in_sizes, int n_in,
                              void* d_out, int out_size, void* d_ws, size_t ws_size,
                              hipStream_t stream) {
    const float* input = (const float*)d_in[0];
    const float* ctx   = (const float*)d_in[1];
    const int*   mask  = (const int*)d_in[2];
    const float* W_in  = (const float*)d_in[3];
    const float* b_in  = (const float*)d_in[4];
    const float* W_ctx = (const float*)d_in[5];
    const float* b_ctx = (const float*)d_in[6];
    const float* wsc   = (const float*)d_in[7];
    const float* W_out = (const float*)d_in[8];
    const float* b_out = (const float*)d_in[9];

    float* x_out = (float*)d_out;               // [B, DI]
    float* attn  = (float*)d_out + B_ * DI;     // [B, S]

    const int NTILE = (B_ * S_) / 64;           // 4096 tiles of 64 rows

    char* ws = (char*)d_ws;
    float* qb = (float*)ws;                    ws += (size_t)B_ * DC * 4;
    unsigned short* WtF = (unsigned short*)ws; ws += (size_t)DC * DC * 2;
    float* scores_ws = (float*)ws;             ws += (size_t)B_ * S_ * 4;
    float* pv_ws = (float*)ws;                 ws += (size_t)NTILE * 512 * 4;
    float* ml_ws = (float*)ws;                 ws += (size_t)NTILE * 2 * 4;

    prep_kernel<<<640, 256, 0, stream>>>(input, W_in, b_in, b_ctx, W_ctx, qb, WtF);
    score_kernel<<<256, 512, 0, stream>>>(ctx, WtF, qb, wsc, mask,
                                          scores_ws, pv_ws, ml_ws);
    tail_kernel<<<dim3(B_, 2), 256, 0, stream>>>(pv_ws, ml_ws, scores_ws, input,
                                                 W_out, b_out, x_out, attn);
}

// Round 8
// 600.358 us; speedup vs baseline: 1.5193x; 1.3036x over previous
//
#include <hip/hip_runtime.h>
#include <hip/hip_bf16.h>
#include <math.h>

#define B_  128
#define S_  2048
#define DI  512
#define DC  512

typedef __attribute__((ext_vector_type(8))) __bf16 bf16x8;
typedef __attribute__((ext_vector_type(4))) float  f32x4;
typedef __attribute__((ext_vector_type(8))) unsigned short us8;

__device__ __forceinline__ float fast_tanh(float x) {
    float e = __expf(2.f * x);
    return 1.f - 2.f * __builtin_amdgcn_rcpf(e + 1.f);
}

__device__ __forceinline__ unsigned short f2bf(float f) {
    unsigned int u = __float_as_uint(f);
    u += 0x7FFF + ((u >> 16) & 1);   // RNE
    return (unsigned short)(u >> 16);
}

__device__ __forceinline__ unsigned int pk2(float a, float b) {
    union { __hip_bfloat162 h; unsigned int u; } c;
    c.h = __float22bfloat162_rn(make_float2(a, b));
    return c.u;
}

__device__ __forceinline__ float bf2f(unsigned int lo16) {
    return __uint_as_float(lo16 << 16);
}

// ---- fused prep: qb (blocks 0..511) + WtF repack (blocks 512..639) ----
__global__ __launch_bounds__(256) void prep_kernel(
    const float* __restrict__ input, const float* __restrict__ W_in,
    const float* __restrict__ b_in, const float* __restrict__ b_ctx,
    const float* __restrict__ W_ctx,
    float* __restrict__ qb, unsigned short* __restrict__ WtF)
{
    __shared__ float sIn[DI];
    __shared__ float part[2][128];
    const int bx = blockIdx.x, t = threadIdx.x;
    if (bx < 512) {
        int b = bx >> 2, cg = bx & 3;
        for (int i = t; i < DI; i += 256) sIn[i] = input[b * DI + i];
        __syncthreads();
        int e = cg * 128 + (t & 127);
        int dh = t >> 7;
        float a = 0.f;
        const float* wp = W_in + (size_t)(dh * 256) * DC + e;
        #pragma unroll 4
        for (int d = 0; d < 256; ++d) a += sIn[dh * 256 + d] * wp[(size_t)d * DC];
        part[dh][t & 127] = a;
        __syncthreads();
        if (t < 128) {
            int ee = cg * 128 + t;
            qb[b * DC + ee] = b_in[ee] + b_ctx[ee] + part[0][t] + part[1][t];
        }
    } else {
        // WtF[s][g][lane][j] = bf16(W_ctx[s*32 + (lane>>4)*8 + j][g*16 + (lane&15)])
        int tid = (bx - 512) * 256 + t;       // [0, 16*32*64)
        int s   = tid >> 11;
        int rem = tid & 2047;
        int g   = rem >> 6;
        int l   = rem & 63;
        int c   = g * 16 + (l & 15);
        int k0  = s * 32 + (l >> 4) * 8;
        us8 wv;
        #pragma unroll
        for (int j = 0; j < 8; ++j)
            wv[j] = f2bf(W_ctx[(size_t)(k0 + j) * DC + c]);
        *(us8*)(WtF + (size_t)tid * 8) = wv;
    }
}

// ---- score kernel staging: one 16-row quarter, 8 regs, one wave = one row ----
struct StQ { float4 a, b; };

__device__ __forceinline__ void loadQ(StQ& q, const float* __restrict__ ctx,
                                      int rowbase, int t) {
    const float* p = ctx + (size_t)(rowbase + (t >> 6)) * DC + (t & 63) * 8;
    q.a = ((const float4*)p)[0];
    q.b = ((const float4*)p)[1];
}

__device__ __forceinline__ void writeQ(const StQ& q, unsigned short* buf,
                                       int qrow, int t) {
    int r = qrow + (t >> 6);
    int cb = (t & 63) * 16;
    uint4 p4 = {pk2(q.a.x, q.a.y), pk2(q.a.z, q.a.w),
                pk2(q.b.x, q.b.y), pk2(q.b.z, q.b.w)};
    *(uint4*)((char*)buf + ((r * 1024 + cb) ^ ((r & 7) << 4))) = p4;
}

#define RBAR() do { \
    asm volatile("s_waitcnt lgkmcnt(0)" ::: "memory"); \
    __builtin_amdgcn_s_barrier(); \
    __builtin_amdgcn_sched_barrier(0); \
} while (0)

// Persistent fused score kernel: 256 blocks (1/CU) x 1024 threads (16 waves).
// 16 contiguous 64-row tiles per block; double-buffered bf16 LDS tiles;
// wave (wr,wc) computes rows [wr*16,+16) x cols [wc*128,+128): acc[8] = 32 VGPR.
// Raw barriers only (lgkmcnt) -> staging loads stream across barriers.
__global__ __launch_bounds__(1024) void score_kernel(
    const float* __restrict__ ctx,          // [B*S, DC] fp32
    const unsigned short* __restrict__ WtF, // fragment-ordered bf16
    const float* __restrict__ qb,           // [B][DC]
    const float* __restrict__ wsc,          // [DC]
    const int* __restrict__ mask,           // [B*S]
    float* __restrict__ scores_ws,          // [B*S]
    float* __restrict__ pv_ws,              // [ntiles][512]
    float* __restrict__ ml_ws)              // [ntiles][2]
{
    __shared__ __align__(16) unsigned short ctxs[2][64 * 512]; // 2 x 64 KB
    __shared__ float sred[4][64];
    __shared__ float sp[64];
    __shared__ float pvpart[2][512];

    const int t = threadIdx.x;
    const int bx = blockIdx.x;
    const int lane = t & 63;
    const int w = t >> 6;                   // wave 0..15
    const int wr = w >> 2;                  // row group (16 rows)
    const int wc = w & 3;                   // col slice (128 cols)
    const int lr = lane & 15, half = lane >> 4;
    const int bidx = bx >> 1;               // batch index (block-constant)

    float wv[8], qv[8];
    #pragma unroll
    for (int fn = 0; fn < 8; ++fn) {
        int j = wc * 128 + fn * 16 + lr;
        wv[fn] = wsc[j];
        qv[fn] = qb[bidx * DC + j];
    }

    StQ Qa, Qb;
    const int t0r = bx * 1024;              // first row of this block
    // ---- prologue: stage tile 0, then issue Q0 of tile 1 ----
    loadQ(Qa, ctx, t0r, t);
    loadQ(Qb, ctx, t0r + 16, t);
    writeQ(Qa, ctxs[0], 0, t);
    loadQ(Qa, ctx, t0r + 32, t);
    writeQ(Qb, ctxs[0], 16, t);
    loadQ(Qb, ctx, t0r + 48, t);
    writeQ(Qa, ctxs[0], 32, t);
    writeQ(Qb, ctxs[0], 48, t);
    loadQ(Qa, ctx, t0r + 64, t);            // Q0 of tile 1
    RBAR();

    int cur = 0;
    #pragma unroll 1
    for (int it = 0; it < 16; ++it) {
        const int tile = bx * 16 + it;
        const int row0 = tile * 64;
        const int nr0 = row0 + 64;          // next tile's rows
        const bool stg = it < 15;
        unsigned short* bufc = ctxs[cur];
        unsigned short* bufn = ctxs[cur ^ 1];

        f32x4 acc[8] = {};

        #pragma unroll 1
        for (int s = 0; s < 16; ++s) {
            if (stg) {
                if (s == 0)      { writeQ(Qa, bufn, 0, t);  loadQ(Qb, ctx, nr0 + 16, t); }
                else if (s == 4) { writeQ(Qb, bufn, 16, t); loadQ(Qa, ctx, nr0 + 32, t); }
                else if (s == 8) { writeQ(Qa, bufn, 32, t); loadQ(Qb, ctx, nr0 + 48, t); }
            }
            bf16x8 bfr[8];
            const us8* wsrc = (const us8*)(WtF + (((size_t)s * 32 + wc * 8) * 64 + lane) * 8);
            #pragma unroll
            for (int fn = 0; fn < 8; ++fn)
                bfr[fn] = *(const bf16x8*)(wsrc + fn * 64);
            const int r_ = wr * 16 + lr;
            bf16x8 af = *(const bf16x8*)((const char*)bufc +
                          ((r_ * 1024 + s * 64 + half * 16) ^ ((r_ & 7) << 4)));
            #pragma unroll
            for (int fn = 0; fn < 8; ++fn)
                acc[fn] = __builtin_amdgcn_mfma_f32_16x16x32_bf16(af, bfr[fn], acc[fn], 0, 0, 0);
        }

        // ---- fold tanh, reduce over cols ----
        float srow[4];
        #pragma unroll
        for (int reg = 0; reg < 4; ++reg) {
            float ssum = 0.f;
            #pragma unroll
            for (int fn = 0; fn < 8; ++fn)
                ssum += wv[fn] * fast_tanh(qv[fn] + acc[fn][reg]);
            srow[reg] = ssum;
        }
        if (stg) writeQ(Qb, bufn, 48, t);    // Q3 (loaded at s==8)
        #pragma unroll
        for (int reg = 0; reg < 4; ++reg) {
            #pragma unroll
            for (int m = 8; m >= 1; m >>= 1)
                srow[reg] += __shfl_xor(srow[reg], m, 64);
            if (lr == 0)
                sred[wc][wr * 16 + half * 4 + reg] = srow[reg];
        }
        RBAR();

        if (t < 64) {                        // wave 0: block softmax partials
            float sc = sred[0][t] + sred[1][t] + sred[2][t] + sred[3][t];
            if (mask[row0 + t] != 0) sc = -1e30f;
            scores_ws[row0 + t] = sc;
            float mx = sc;
            #pragma unroll
            for (int m = 32; m >= 1; m >>= 1) mx = fmaxf(mx, __shfl_xor(mx, m, 64));
            float pe = __expf(sc - mx);
            sp[t] = pe;
            float ls = pe;
            #pragma unroll
            for (int m = 32; m >= 1; m >>= 1) ls += __shfl_xor(ls, m, 64);
            if (t == 0) {
                ml_ws[tile * 2]     = mx;
                ml_ws[tile * 2 + 1] = ls;
            }
        }
        RBAR();

        if (it < 14) loadQ(Qa, ctx, nr0 + 64, t);   // Q0 of tile+2: hides under pv

        // ---- pv partials from LDS bf16 tile ----
        {
            const int rh = t >> 9, colp = t & 511;
            float a0 = 0.f;
            #pragma unroll 8
            for (int s2 = 0; s2 < 32; ++s2) {
                int r = rh * 32 + s2;
                unsigned int u = *(const unsigned short*)
                    ((const char*)bufc + ((r * 1024 + colp * 2) ^ ((r & 7) << 4)));
                a0 += sp[r] * bf2f(u);
            }
            pvpart[rh][colp] = a0;
        }
        RBAR();
        if (t < 512)
            pv_ws[(size_t)tile * 512 + t] = pvpart[0][t] + pvpart[1][t];

        cur ^= 1;
    }
}

// ---- fused tail: exact softmax merge + attn + ctxv + output GEMM ----
__global__ __launch_bounds__(256) void tail_kernel(
    const float* __restrict__ pv, const float* __restrict__ ml,
    const float* __restrict__ scores, const float* __restrict__ input,
    const float* __restrict__ W_out, const float* __restrict__ b_out,
    float* __restrict__ x, float* __restrict__ attn)
{
    int b = blockIdx.x, hf = blockIdx.y, t = threadIdx.x;
    __shared__ float sw[32];
    __shared__ float scm[1024];
    __shared__ float mlds[2];
    if (t < 32) {
        float m = ml[(b * 32 + t) * 2];
        float l = ml[(b * 32 + t) * 2 + 1];
        float mx = m;
        #pragma unroll
        for (int mm = 16; mm >= 1; mm >>= 1) mx = fmaxf(mx, __shfl_xor(mx, mm, 64));
        float wgt = __expf(m - mx);
        sw[t] = wgt;
        float ls = wgt * l;
        #pragma unroll
        for (int mm = 16; mm >= 1; mm >>= 1) ls += __shfl_xor(ls, mm, 64);
        if (t == 0) { mlds[0] = mx; mlds[1] = 1.f / ls; }
    }
    __syncthreads();
    const float mstar = mlds[0], invL = mlds[1];

    {   // ctxv -> scm[0..511]
        int d0 = t * 2;
        float c0 = 0.f, c1 = 0.f;
        #pragma unroll 4
        for (int j = 0; j < 32; ++j) {
            float wgt = sw[j];
            const float2 v = *(const float2*)(pv + (size_t)(b * 32 + j) * 512 + d0);
            c0 += wgt * v.x; c1 += wgt * v.y;
        }
        scm[d0] = c0 * invL; scm[d0 + 1] = c1 * invL;
    }
    for (int i = t; i < DI; i += 256) scm[512 + i] = input[b * DI + i];
    if (hf == 0) {
        #pragma unroll
        for (int k = 0; k < 8; ++k) {
            int s = k * 256 + t;
            attn[(size_t)b * S_ + s] = __expf(scores[(size_t)b * S_ + s] - mstar) * invL;
        }
    }
    __syncthreads();

    int e = hf * 256 + t;
    float a = b_out[e];
    #pragma unroll 4
    for (int d = 0; d < 1024; ++d) a += scm[d] * W_out[(size_t)d * DI + e];
    x[b * DI + e] = fast_tanh(a);
}

extern "C" void kernel_launch(void* const* d_in, const int* in_sizes, int n_in,
                              void* d_out, int out_size, void* d_ws, size_t ws_size,
                              hipStream_t stream) {
    const float* input = (const float*)d_in[0];
    const float* ctx   = (const float*)d_in[1];
    const int*   mask  = (const int*)d_in[2];
    const float* W_in  = (const float*)d_in[3];
    const float* b_in  = (const float*)d_in[4];
    const float* W_ctx = (const float*)d_in[5];
    const float* b_ctx = (const float*)d_in[6];
    const float* wsc   = (const float*)d_in[7];
    const float* W_out = (const float*)d_in[8];
    const float* b_out = (const float*)d_in[9];

    float* x_out = (float*)d_out;               // [B, DI]
    float* attn  = (float*)d_out + B_ * DI;     // [B, S]

    const int NTILE = (B_ * S_) / 64;           // 4096 tiles of 64 rows

    char* ws = (char*)d_ws;
    float* qb = (float*)ws;                    ws += (size_t)B_ * DC * 4;
    unsigned short* WtF = (unsigned short*)ws; ws += (size_t)DC * DC * 2;
    float* scores_ws = (float*)ws;             ws += (size_t)B_ * S_ * 4;
    float* pv_ws = (float*)ws;                 ws += (size_t)NTILE * 512 * 4;
    float* ml_ws = (float*)ws;                 ws += (size_t)NTILE * 2 * 4;

    prep_kernel<<<640, 256, 0, stream>>>(input, W_in, b_in, b_ctx, W_ctx, qb, WtF);
    score_kernel<<<256, 1024, 0, stream>>>(ctx, WtF, qb, wsc, mask,
                                           scores_ws, pv_ws, ml_ws);
    tail_kernel<<<dim3(B_, 2), 256, 0, stream>>>(pv_ws, ml_ws, scores_ws, input,
                                                 W_out, b_out, x_out, attn);
}

// Round 9
// 350.141 us; speedup vs baseline: 2.6050x; 1.7146x over previous
//
#include <hip/hip_runtime.h>
#include <hip/hip_bf16.h>
#include <math.h>

#define B_  128
#define S_  2048
#define DI  512
#define DC  512

typedef __attribute__((ext_vector_type(8))) __bf16 bf16x8;
typedef __attribute__((ext_vector_type(4))) float  f32x4;
typedef __attribute__((ext_vector_type(8))) unsigned short us8;

__device__ __forceinline__ float fast_tanh(float x) {
    float e = __expf(2.f * x);
    return 1.f - 2.f * __builtin_amdgcn_rcpf(e + 1.f);
}

__device__ __forceinline__ unsigned short f2bf(float f) {
    unsigned int u = __float_as_uint(f);
    u += 0x7FFF + ((u >> 16) & 1);   // RNE
    return (unsigned short)(u >> 16);
}

__device__ __forceinline__ unsigned int pk2(float a, float b) {
    union { __hip_bfloat162 h; unsigned int u; } c;
    c.h = __float22bfloat162_rn(make_float2(a, b));
    return c.u;
}

__device__ __forceinline__ float bf2f(unsigned int lo16) {
    return __uint_as_float(lo16 << 16);
}

// ---- fused prep: qb (blocks 0..511) + WtF repack (blocks 512..639) ----
__global__ __launch_bounds__(256) void prep_kernel(
    const float* __restrict__ input, const float* __restrict__ W_in,
    const float* __restrict__ b_in, const float* __restrict__ b_ctx,
    const float* __restrict__ W_ctx,
    float* __restrict__ qb, unsigned short* __restrict__ WtF)
{
    __shared__ float sIn[DI];
    __shared__ float part[2][128];
    const int bx = blockIdx.x, t = threadIdx.x;
    if (bx < 512) {
        int b = bx >> 2, cg = bx & 3;
        for (int i = t; i < DI; i += 256) sIn[i] = input[b * DI + i];
        __syncthreads();
        int e = cg * 128 + (t & 127);
        int dh = t >> 7;
        float a = 0.f;
        const float* wp = W_in + (size_t)(dh * 256) * DC + e;
        #pragma unroll 4
        for (int d = 0; d < 256; ++d) a += sIn[dh * 256 + d] * wp[(size_t)d * DC];
        part[dh][t & 127] = a;
        __syncthreads();
        if (t < 128) {
            int ee = cg * 128 + t;
            qb[b * DC + ee] = b_in[ee] + b_ctx[ee] + part[0][t] + part[1][t];
        }
    } else {
        // WtF[s][g][lane][j] = bf16(W_ctx[s*32 + (lane>>4)*8 + j][g*16 + (lane&15)])
        int tid = (bx - 512) * 256 + t;       // [0, 16*32*64)
        int s   = tid >> 11;
        int rem = tid & 2047;
        int g   = rem >> 6;
        int l   = rem & 63;
        int c   = g * 16 + (l & 15);
        int k0  = s * 32 + (l >> 4) * 8;
        us8 wv;
        #pragma unroll
        for (int j = 0; j < 8; ++j)
            wv[j] = f2bf(W_ctx[(size_t)(k0 + j) * DC + c]);
        *(us8*)(WtF + (size_t)tid * 8) = wv;
    }
}

__device__ __forceinline__ void bfrLoad(bf16x8 (&b)[4],
                                        const unsigned short* __restrict__ WtF,
                                        int s, int w, int lane) {
    const us8* ws = (const us8*)(WtF + (((size_t)s * 32 + w * 4) * 64 + lane) * 8);
    #pragma unroll
    for (int fn = 0; fn < 4; ++fn) b[fn] = *(const bf16x8*)(ws + fn * 64);
}

// Fused score kernel (round-4 structure + bfr prefetch pipeline):
// 4096 blocks x 512 threads (8 waves), 2 blocks/CU, one 64-row tile each.
// Wave w owns cols [w*64, +64) x all 64 rows: acc[4][4].
__global__ __launch_bounds__(512)
__attribute__((amdgpu_waves_per_eu(4, 4)))
void score_kernel(
    const float* __restrict__ ctx,          // [B*S, DC] fp32
    const unsigned short* __restrict__ WtF, // fragment-ordered bf16
    const float* __restrict__ qb,           // [B][DC]
    const float* __restrict__ wsc,          // [DC]
    const int* __restrict__ mask,           // [B*S]
    float* __restrict__ scores_ws,          // [B*S]
    float* __restrict__ pv_ws,              // [ntiles][512]
    float* __restrict__ ml_ws)              // [ntiles][2]
{
    __shared__ __align__(16) unsigned short ctxs[64 * 512];  // 64 KB swizzled
    __shared__ float sred[8][64];
    __shared__ float sp[64];

    const int t = threadIdx.x;
    const int row0 = blockIdx.x * 64;
    const int bidx = row0 >> 11;
    const int lane = t & 63;
    const int w = t >> 6;                   // wave 0..7 = col slice
    const int lr = lane & 15, half = lane >> 4;

    // issue step-0 B fragments first: in flight during staging
    bf16x8 bc[4], bn[4];
    bfrLoad(bc, WtF, 0, w, lane);

    // ---- stage ctx -> bf16 LDS (pairwise ILP) ----
    #pragma unroll
    for (int ii = 0; ii < 4; ++ii) {
        int u0 = (2 * ii) * 512 + t;
        int u1 = (2 * ii + 1) * 512 + t;
        int r0 = u0 >> 6, k0 = u0 & 63;
        int r1 = u1 >> 6, k1 = u1 & 63;
        const float4* s0 = (const float4*)(ctx + (size_t)(row0 + r0) * DC + k0 * 8);
        const float4* s1 = (const float4*)(ctx + (size_t)(row0 + r1) * DC + k1 * 8);
        float4 a0 = s0[0], b0 = s0[1];
        float4 a1 = s1[0], b1 = s1[1];
        uint4 p0 = {pk2(a0.x, a0.y), pk2(a0.z, a0.w), pk2(b0.x, b0.y), pk2(b0.z, b0.w)};
        uint4 p1 = {pk2(a1.x, a1.y), pk2(a1.z, a1.w), pk2(b1.x, b1.y), pk2(b1.z, b1.w)};
        *(uint4*)((char*)ctxs + ((r0 * 1024 + k0 * 16) ^ ((r0 & 7) << 4))) = p0;
        *(uint4*)((char*)ctxs + ((r1 * 1024 + k1 * 16) ^ ((r1 & 7) << 4))) = p1;
    }
    __syncthreads();

    // ---- K-loop: barrier-free, one-step B prefetch ----
    f32x4 acc[4][4] = {};
    #pragma unroll 2
    for (int s = 0; s < 16; ++s) {
        if (s < 15) bfrLoad(bn, WtF, s + 1, w, lane);
        bf16x8 af[4];
        #pragma unroll
        for (int fm = 0; fm < 4; ++fm) {
            int r = fm * 16 + lr;
            af[fm] = *(const bf16x8*)((const char*)ctxs +
                        ((r * 1024 + s * 64 + half * 16) ^ ((r & 7) << 4)));
        }
        #pragma unroll
        for (int fm = 0; fm < 4; ++fm)
            #pragma unroll
            for (int fn = 0; fn < 4; ++fn)
                acc[fm][fn] = __builtin_amdgcn_mfma_f32_16x16x32_bf16(
                    af[fm], bc[fn], acc[fm][fn], 0, 0, 0);
        if (s < 15) {
            #pragma unroll
            for (int q = 0; q < 4; ++q) bc[q] = bn[q];
        }
    }

    // ---- epilogue: fold tanh, reduce rows ----
    float wv[4], qv[4];
    #pragma unroll
    for (int fn = 0; fn < 4; ++fn) {
        int j = w * 64 + fn * 16 + lr;
        wv[fn] = wsc[j];
        qv[fn] = qb[bidx * DC + j];
    }
    #pragma unroll
    for (int fm = 0; fm < 4; ++fm) {
        #pragma unroll
        for (int reg = 0; reg < 4; ++reg) {
            float ssum = 0.f;
            #pragma unroll
            for (int fn = 0; fn < 4; ++fn)
                ssum += wv[fn] * fast_tanh(qv[fn] + acc[fm][fn][reg]);
            #pragma unroll
            for (int m = 8; m >= 1; m >>= 1)
                ssum += __shfl_xor(ssum, m, 64);
            if (lr == 0)
                sred[w][fm * 16 + half * 4 + reg] = ssum;
        }
    }
    __syncthreads();

    if (t < 64) {                        // wave 0: block softmax partials
        float sc = sred[0][t] + sred[1][t] + sred[2][t] + sred[3][t]
                 + sred[4][t] + sred[5][t] + sred[6][t] + sred[7][t];
        if (mask[row0 + t] != 0) sc = -1e30f;
        scores_ws[row0 + t] = sc;
        float mx = sc;
        #pragma unroll
        for (int m = 32; m >= 1; m >>= 1) mx = fmaxf(mx, __shfl_xor(mx, m, 64));
        float pe = __expf(sc - mx);
        sp[t] = pe;
        float ls = pe;
        #pragma unroll
        for (int m = 32; m >= 1; m >>= 1) ls += __shfl_xor(ls, m, 64);
        if (t == 0) {
            ml_ws[blockIdx.x * 2]     = mx;
            ml_ws[blockIdx.x * 2 + 1] = ls;
        }
    }
    __syncthreads();

    // ---- pv partial: thread t = col t, rows from LDS ----
    float a0 = 0.f;
    #pragma unroll 8
    for (int s2 = 0; s2 < 64; ++s2) {
        unsigned int u = *(const unsigned short*)
            ((const char*)ctxs + ((s2 * 1024 + t * 2) ^ ((s2 & 7) << 4)));
        a0 += sp[s2] * bf2f(u);
    }
    pv_ws[(size_t)blockIdx.x * 512 + t] = a0;
}

// ---- fused tail: exact softmax merge + attn + ctxv + output GEMM ----
__global__ __launch_bounds__(256) void tail_kernel(
    const float* __restrict__ pv, const float* __restrict__ ml,
    const float* __restrict__ scores, const float* __restrict__ input,
    const float* __restrict__ W_out, const float* __restrict__ b_out,
    float* __restrict__ x, float* __restrict__ attn)
{
    int b = blockIdx.x, hf = blockIdx.y, t = threadIdx.x;
    __shared__ float sw[32];
    __shared__ float scm[1024];
    __shared__ float mlds[2];
    if (t < 32) {
        float m = ml[(b * 32 + t) * 2];
        float l = ml[(b * 32 + t) * 2 + 1];
        float mx = m;
        #pragma unroll
        for (int mm = 16; mm >= 1; mm >>= 1) mx = fmaxf(mx, __shfl_xor(mx, mm, 64));
        float wgt = __expf(m - mx);
        sw[t] = wgt;
        float ls = wgt * l;
        #pragma unroll
        for (int mm = 16; mm >= 1; mm >>= 1) ls += __shfl_xor(ls, mm, 64);
        if (t == 0) { mlds[0] = mx; mlds[1] = 1.f / ls; }
    }
    __syncthreads();
    const float mstar = mlds[0], invL = mlds[1];

    {   // ctxv -> scm[0..511]
        int d0 = t * 2;
        float c0 = 0.f, c1 = 0.f;
        #pragma unroll 4
        for (int j = 0; j < 32; ++j) {
            float wgt = sw[j];
            const float2 v = *(const float2*)(pv + (size_t)(b * 32 + j) * 512 + d0);
            c0 += wgt * v.x; c1 += wgt * v.y;
        }
        scm[d0] = c0 * invL; scm[d0 + 1] = c1 * invL;
    }
    for (int i = t; i < DI; i += 256) scm[512 + i] = input[b * DI + i];
    if (hf == 0) {
        #pragma unroll
        for (int k = 0; k < 8; ++k) {
            int s = k * 256 + t;
            attn[(size_t)b * S_ + s] = __expf(scores[(size_t)b * S_ + s] - mstar) * invL;
        }
    }
    __syncthreads();

    int e = hf * 256 + t;
    float a = b_out[e];
    #pragma unroll 4
    for (int d = 0; d < 1024; ++d) a += scm[d] * W_out[(size_t)d * DI + e];
    x[b * DI + e] = fast_tanh(a);
}

extern "C" void kernel_launch(void* const* d_in, const int* in_sizes, int n_in,
                              void* d_out, int out_size, void* d_ws, size_t ws_size,
                              hipStream_t stream) {
    const float* input = (const float*)d_in[0];
    const float* ctx   = (const float*)d_in[1];
    const int*   mask  = (const int*)d_in[2];
    const float* W_in  = (const float*)d_in[3];
    const float* b_in  = (const float*)d_in[4];
    const float* W_ctx = (const float*)d_in[5];
    const float* b_ctx = (const float*)d_in[6];
    const float* wsc   = (const float*)d_in[7];
    const float* W_out = (const float*)d_in[8];
    const float* b_out = (const float*)d_in[9];

    float* x_out = (float*)d_out;               // [B, DI]
    float* attn  = (float*)d_out + B_ * DI;     // [B, S]

    const int NTILE = (B_ * S_) / 64;           // 4096 tiles of 64 rows

    char* ws = (char*)d_ws;
    float* qb = (float*)ws;                    ws += (size_t)B_ * DC * 4;
    unsigned short* WtF = (unsigned short*)ws; ws += (size_t)DC * DC * 2;
    float* scores_ws = (float*)ws;             ws += (size_t)B_ * S_ * 4;
    float* pv_ws = (float*)ws;                 ws += (size_t)NTILE * 512 * 4;
    float* ml_ws = (float*)ws;                 ws += (size_t)NTILE * 2 * 4;

    prep_kernel<<<640, 256, 0, stream>>>(input, W_in, b_in, b_ctx, W_ctx, qb, WtF);
    score_kernel<<<NTILE, 512, 0, stream>>>(ctx, WtF, qb, wsc, mask,
                                            scores_ws, pv_ws, ml_ws);
    tail_kernel<<<dim3(B_, 2), 256, 0, stream>>>(pv_ws, ml_ws, scores_ws, input,
                                                 W_out, b_out, x_out, attn);
}